// Round 1
// baseline (835.425 us; speedup 1.0000x reference)
//
#include <hip/hip_runtime.h>
#include <cstdint>
#include <cstddef>

typedef __bf16 bf16;
typedef bf16  bf16x8 __attribute__((ext_vector_type(8)));
typedef float f32x4  __attribute__((ext_vector_type(4)));

#define GLOBAL_AS __attribute__((address_space(1)))
#define LDS_AS    __attribute__((address_space(3)))

__device__ __forceinline__ void ldg_lds16(const void* g, void* l) {
  __builtin_amdgcn_global_load_lds((const GLOBAL_AS void*)g, (LDS_AS void*)l, 16, 0, 0);
}

// problem constants
constexpr int NB    = 2;
constexpr int SQ    = 2048;
constexpr int HID   = 1024;
constexpr int NHEAD = 16;
constexpr int HD    = 64;
constexpr int NROW  = NB * SQ;        // 4096
constexpr int KA    = HID + HID * 8;  // 9216 (silu part + 8 spline coeffs per dim)
constexpr int NO    = 3 * HID;        // 3072

// ---------------------------------------------------------------------------
// Kernel 1: augmented activation A[n] = [silu(x[n,:]), b_splines(x[n,:]).flat]
// one thread per (n, i); writes 1 bf16 (silu) + 8 bf16 (spline basis, 16B store)
// ---------------------------------------------------------------------------
__global__ __launch_bounds__(256) void build_a(const float* __restrict__ X,
                                               const float* __restrict__ Grid,
                                               bf16* __restrict__ A) {
  int idx = blockIdx.x * 256 + threadIdx.x;  // n*1024 + i
  int n = idx >> 10, i = idx & 1023;
  float x = X[idx];
  float s = x / (1.0f + __expf(-x));  // silu
  A[(size_t)n * KA + i] = (bf16)s;

  float kn[12];
#pragma unroll
  for (int t = 0; t < 12; t++) kn[t] = Grid[i * 12 + t];
  float bs[11];
#pragma unroll
  for (int t = 0; t < 11; t++) bs[t] = (x >= kn[t] && x < kn[t + 1]) ? 1.0f : 0.0f;
#pragma unroll
  for (int p = 1; p <= 3; p++) {
#pragma unroll
    for (int t = 0; t + p < 11; t++) {
      bs[t] = (x - kn[t]) / (kn[t + p] - kn[t]) * bs[t]
            + (kn[t + p + 1] - x) / (kn[t + p + 1] - kn[t + 1]) * bs[t + 1];
    }
  }
  union { bf16 h[8]; uint4 u; } pk;
#pragma unroll
  for (int t = 0; t < 8; t++) pk.h[t] = (bf16)bs[t];
  *(uint4*)(A + (size_t)n * KA + HID + i * 8) = pk.u;  // 16B aligned
}

// ---------------------------------------------------------------------------
// Kernel 2: augmented weight W'[o] = [base_weight[o], spline_w*scaler flat],
// with per-head rotation folded into the q/k row blocks (and 1/8 into q).
// block = (jtile of 32 cols, head). LDS: R (16KB) + Wfull tile 192x32 (24KB).
// ---------------------------------------------------------------------------
__global__ __launch_bounds__(256) void build_w(const float* __restrict__ BW,
                                               const float* __restrict__ SW,
                                               const float* __restrict__ SS,
                                               const float* __restrict__ R,
                                               bf16* __restrict__ Wp) {
  __shared__ float Rl[64 * 64];
  __shared__ float Wt[192 * 32];
  int jt = blockIdx.x, h = blockIdx.y, tid = threadIdx.x;
  for (int idx = tid; idx < 4096; idx += 256) Rl[idx] = R[idx];
  for (int idx = tid; idx < 6144; idx += 256) {
    int rr = idx >> 5, jj = idx & 31;
    int o = h * 192 + rr;
    int j = jt * 32 + jj;
    float v;
    if (j < HID) {
      v = BW[(size_t)o * HID + j];
    } else {
      int jm = j - HID, ii = jm >> 3, t = jm & 7;
      v = SW[((size_t)o * HID + ii) * 8 + t] * SS[(size_t)o * HID + ii];
    }
    Wt[idx] = v;
  }
  __syncthreads();
  for (int idx = tid; idx < 6144; idx += 256) {
    int rr = idx >> 5, jj = idx & 31;
    float outv;
    if (rr < 128) {                       // q rows (0..63) and k rows (64..127): rotate
      int m = rr & 63;
      int base = (rr < 64) ? 0 : 64;
      float acc = 0.f;
#pragma unroll
      for (int d = 0; d < 64; d++) acc += Rl[m * 64 + d] * Wt[(base + d) * 32 + jj];
      outv = (rr < 64) ? acc * 0.125f : acc;  // fold 1/sqrt(HD) into q
    } else {
      outv = Wt[idx];                     // v rows: passthrough
    }
    Wp[(size_t)(h * 192 + rr) * KA + jt * 32 + jj] = (bf16)outv;
  }
}

// ---------------------------------------------------------------------------
// Kernel 3: out_w fp32 -> bf16
// ---------------------------------------------------------------------------
__global__ __launch_bounds__(256) void conv_wout(const float* __restrict__ OW,
                                                 bf16* __restrict__ WOB) {
  int i = (blockIdx.x * 256 + threadIdx.x) * 4;
  float4 f = *(const float4*)(OW + i);
  union { bf16 h[4]; uint2 u; } p;
  p.h[0] = (bf16)f.x; p.h[1] = (bf16)f.y; p.h[2] = (bf16)f.z; p.h[3] = (bf16)f.w;
  *(uint2*)(WOB + i) = p.u;
}

// ---------------------------------------------------------------------------
// GEMM mainloop (m97 structure): C[m][n] = sum_k A[m][k] * B[n][k] (B^T input)
// 128x128 tile, BK=32, 4 waves in 2x2, each wave 64x64 = 4x4 MFMA 16x16x32.
// ---------------------------------------------------------------------------
template <int K>
__device__ __forceinline__ void gemm_tile(const bf16* __restrict__ A,
                                          const bf16* __restrict__ Bw,
                                          int rowBase, int colBase,
                                          bf16* As, bf16* Bs, f32x4 acc[4][4]) {
  const int tid  = threadIdx.x;
  const int lane = tid & 63, wave = tid >> 6;
  const int wm = (wave >> 1) * 64, wn = (wave & 1) * 64;
  const int l15 = lane & 15, quad = lane >> 4;
  const int rA = tid >> 2, sA = (tid & 3) * 8;  // staging: 4x16B chunks per 32-col row
#pragma unroll
  for (int mi = 0; mi < 4; mi++)
#pragma unroll
    for (int ni = 0; ni < 4; ni++) acc[mi][ni] = (f32x4){0.f, 0.f, 0.f, 0.f};

  const bf16* Ag1 = A  + (size_t)(rowBase + rA) * K + sA;
  const bf16* Ag2 = A  + (size_t)(rowBase + 64 + rA) * K + sA;
  const bf16* Bg1 = Bw + (size_t)(colBase + rA) * K + sA;
  const bf16* Bg2 = Bw + (size_t)(colBase + 64 + rA) * K + sA;

  for (int k0 = 0; k0 < K; k0 += 32) {
    __syncthreads();  // previous compute done before LDS overwrite
    ldg_lds16(Ag1 + k0, As + tid * 8);
    ldg_lds16(Ag2 + k0, As + 2048 + tid * 8);
    ldg_lds16(Bg1 + k0, Bs + tid * 8);
    ldg_lds16(Bg2 + k0, Bs + 2048 + tid * 8);
    __syncthreads();  // drains vmcnt (compiler inserts waitcnt before barrier)
    bf16x8 af[4], bfr[4];
#pragma unroll
    for (int mi = 0; mi < 4; mi++)
      af[mi] = *(const bf16x8*)(As + (wm + mi * 16 + l15) * 32 + quad * 8);
#pragma unroll
    for (int ni = 0; ni < 4; ni++)
      bfr[ni] = *(const bf16x8*)(Bs + (wn + ni * 16 + l15) * 32 + quad * 8);
#pragma unroll
    for (int mi = 0; mi < 4; mi++)
#pragma unroll
      for (int ni = 0; ni < 4; ni++)
        acc[mi][ni] = __builtin_amdgcn_mfma_f32_16x16x32_bf16(af[mi], bfr[ni], acc[mi][ni], 0, 0, 0);
  }
}

// ---------------------------------------------------------------------------
// Kernel 4: qkv = Aaug @ W'^T  (4096 x 3072 x 9216), split-store into
// qr/kr/v buffers laid out [b][h][s][d] in bf16 (q pre-rotated+scaled, k pre-rotated)
// ---------------------------------------------------------------------------
__global__ __launch_bounds__(256) void gemm_qkv(const bf16* __restrict__ A,
                                                const bf16* __restrict__ W,
                                                bf16* __restrict__ QR,
                                                bf16* __restrict__ KR,
                                                bf16* __restrict__ VV) {
  __shared__ __align__(16) bf16 As[128 * 32];
  __shared__ __align__(16) bf16 Bs[128 * 32];
  f32x4 acc[4][4];
  const int rowBase = blockIdx.y * 128, colBase = blockIdx.x * 128;
  gemm_tile<KA>(A, W, rowBase, colBase, As, Bs, acc);

  const int tid = threadIdx.x, lane = tid & 63, wave = tid >> 6;
  const int wm = (wave >> 1) * 64, wn = (wave & 1) * 64;
  const int l15 = lane & 15, quad = lane >> 4;
#pragma unroll
  for (int mi = 0; mi < 4; mi++)
#pragma unroll
    for (int ni = 0; ni < 4; ni++)
#pragma unroll
      for (int r = 0; r < 4; r++) {
        int row = rowBase + wm + mi * 16 + quad * 4 + r;  // n = b*2048+s
        int col = colBase + wn + ni * 16 + l15;           // o = h*192+c
        int b = row >> 11, s = row & 2047;
        int hh = col / 192, c = col - hh * 192;
        size_t base = ((size_t)(b * NHEAD + hh) * SQ + s) * HD;
        float v = acc[mi][ni][r];
        if (c < 64)        QR[base + c] = (bf16)v;
        else if (c < 128)  KR[base + c - 64] = (bf16)v;
        else               VV[base + c - 128] = (bf16)v;
      }
}

// ---------------------------------------------------------------------------
// Kernel 5: flash attention. block = (qtile of 128 rows, bh). 4 waves, each
// owns 32 q-rows. K-tile = 64 keys. Online softmax fp32; P via LDS roundtrip.
// qr already has 1/8 scale folded in. Writes ctx bf16 as [b*S+s][h*64+d].
// ---------------------------------------------------------------------------
__global__ __launch_bounds__(256) void attn(const bf16* __restrict__ QR,
                                            const bf16* __restrict__ KR,
                                            const bf16* __restrict__ VV,
                                            bf16* __restrict__ CTXB) {
  __shared__ __align__(16) bf16 Qs[128 * 64];
  __shared__ __align__(16) bf16 Ks[64 * 64];
  __shared__ __align__(16) bf16 Vt[64 * 64];   // transposed: [d][key]
  __shared__ __align__(16) bf16 Ps[128 * 64];
  const int bh = blockIdx.y;
  const int b = bh >> 4, h = bh & 15;
  const int qbase = blockIdx.x * 128;
  const bf16* Q = QR + (size_t)bh * SQ * HD;
  const bf16* Kp = KR + (size_t)bh * SQ * HD;
  const bf16* V = VV + (size_t)bh * SQ * HD;
  const int tid = threadIdx.x, lane = tid & 63, wave = tid >> 6;
  const int l15 = lane & 15, quad = lane >> 4;

  // stage Q tile (128 rows x 64 d): 1024 16B chunks
#pragma unroll
  for (int i = 0; i < 4; i++) {
    int c = i * 256 + tid;
    int row = c >> 3, seg = c & 7;
    ldg_lds16(Q + (size_t)(qbase + row) * HD + seg * 8, Qs + c * 8);
  }

  float mstate[2][4], lstate[2][4];
  f32x4 ctxacc[2][4];
#pragma unroll
  for (int mi = 0; mi < 2; mi++)
#pragma unroll
    for (int r = 0; r < 4; r++) { mstate[mi][r] = -1e30f; lstate[mi][r] = 0.f; }
#pragma unroll
  for (int mi = 0; mi < 2; mi++)
#pragma unroll
    for (int nd = 0; nd < 4; nd++) ctxacc[mi][nd] = (f32x4){0.f, 0.f, 0.f, 0.f};

  for (int kt = 0; kt < SQ / 64; kt++) {
    const int kbase = kt * 64;
    if (kt) __syncthreads();  // prev PV reads done before restaging
    // stage K tile (64x64): 512 chunks
#pragma unroll
    for (int i = 0; i < 2; i++) {
      int c = i * 256 + tid;
      int row = c >> 3, seg = c & 7;
      ldg_lds16(Kp + (size_t)(kbase + row) * HD + seg * 8, Ks + c * 8);
    }
    // stage V tile transposed
#pragma unroll
    for (int i = 0; i < 2; i++) {
      int c = i * 256 + tid;
      int key = c >> 3, seg = c & 7;
      bf16x8 v8 = *(const bf16x8*)(V + (size_t)(kbase + key) * HD + seg * 8);
#pragma unroll
      for (int jj = 0; jj < 8; jj++) Vt[(seg * 8 + jj) * 64 + key] = v8[jj];
    }
    __syncthreads();

    // S = Q K^T  (wave's 32 rows x 64 keys)
    f32x4 sacc[2][4];
#pragma unroll
    for (int mi = 0; mi < 2; mi++)
#pragma unroll
      for (int nj = 0; nj < 4; nj++) sacc[mi][nj] = (f32x4){0.f, 0.f, 0.f, 0.f};
#pragma unroll
    for (int kc = 0; kc < 2; kc++) {
      bf16x8 af[2], bfr[4];
#pragma unroll
      for (int mi = 0; mi < 2; mi++)
        af[mi] = *(const bf16x8*)(Qs + (wave * 32 + mi * 16 + l15) * 64 + kc * 32 + quad * 8);
#pragma unroll
      for (int nj = 0; nj < 4; nj++)
        bfr[nj] = *(const bf16x8*)(Ks + (nj * 16 + l15) * 64 + kc * 32 + quad * 8);
#pragma unroll
      for (int mi = 0; mi < 2; mi++)
#pragma unroll
        for (int nj = 0; nj < 4; nj++)
          sacc[mi][nj] = __builtin_amdgcn_mfma_f32_16x16x32_bf16(af[mi], bfr[nj], sacc[mi][nj], 0, 0, 0);
    }

    // online softmax per owned row (rows: wave*32 + mi*16 + quad*4 + r)
#pragma unroll
    for (int mi = 0; mi < 2; mi++) {
#pragma unroll
      for (int r = 0; r < 4; r++) {
        float tm = -1e30f;
#pragma unroll
        for (int nj = 0; nj < 4; nj++) tm = fmaxf(tm, sacc[mi][nj][r]);
#pragma unroll
        for (int off = 1; off < 16; off <<= 1) tm = fmaxf(tm, __shfl_xor(tm, off));
        float mold = mstate[mi][r];
        float mnew = fmaxf(mold, tm);
        float alpha = __expf(mold - mnew);
        float rs = 0.f;
#pragma unroll
        for (int nj = 0; nj < 4; nj++) {
          float p = __expf(sacc[mi][nj][r] - mnew);
          sacc[mi][nj][r] = p;
          rs += p;
        }
#pragma unroll
        for (int off = 1; off < 16; off <<= 1) rs += __shfl_xor(rs, off);
        lstate[mi][r] = lstate[mi][r] * alpha + rs;
        mstate[mi][r] = mnew;
#pragma unroll
        for (int nd = 0; nd < 4; nd++) ctxacc[mi][nd][r] *= alpha;
      }
      // write P (C/D layout) -> LDS for A-operand reuse
#pragma unroll
      for (int nj = 0; nj < 4; nj++)
#pragma unroll
        for (int r = 0; r < 4; r++)
          Ps[(wave * 32 + mi * 16 + quad * 4 + r) * 64 + nj * 16 + l15] = (bf16)sacc[mi][nj][r];
    }
    __syncthreads();  // conservative: P visible before PV reads

    // ctx += P V
#pragma unroll
    for (int kc = 0; kc < 2; kc++) {
      bf16x8 af[2], bfr[4];
#pragma unroll
      for (int mi = 0; mi < 2; mi++)
        af[mi] = *(const bf16x8*)(Ps + (wave * 32 + mi * 16 + l15) * 64 + kc * 32 + quad * 8);
#pragma unroll
      for (int nd = 0; nd < 4; nd++)
        bfr[nd] = *(const bf16x8*)(Vt + (nd * 16 + l15) * 64 + kc * 32 + quad * 8);
#pragma unroll
      for (int mi = 0; mi < 2; mi++)
#pragma unroll
        for (int nd = 0; nd < 4; nd++)
          ctxacc[mi][nd] = __builtin_amdgcn_mfma_f32_16x16x32_bf16(af[mi], bfr[nd], ctxacc[mi][nd], 0, 0, 0);
    }
  }

  // epilogue: ctx/l -> bf16 [b*S+s][h*64+d]
#pragma unroll
  for (int mi = 0; mi < 2; mi++)
#pragma unroll
    for (int nd = 0; nd < 4; nd++)
#pragma unroll
      for (int r = 0; r < 4; r++) {
        int srow = qbase + wave * 32 + mi * 16 + quad * 4 + r;
        float val = ctxacc[mi][nd][r] / lstate[mi][r];
        CTXB[(size_t)(b * SQ + srow) * HID + h * HD + nd * 16 + l15] = (bf16)val;
      }
}

// ---------------------------------------------------------------------------
// Kernel 6: out = ctx @ out_w^T + out_b  (4096 x 1024 x 1024), fp32 out
// ---------------------------------------------------------------------------
__global__ __launch_bounds__(256) void gemm_out(const bf16* __restrict__ CTX,
                                                const bf16* __restrict__ WOB,
                                                const float* __restrict__ OB,
                                                float* __restrict__ OUT) {
  __shared__ __align__(16) bf16 As[128 * 32];
  __shared__ __align__(16) bf16 Bs[128 * 32];
  f32x4 acc[4][4];
  const int rowBase = blockIdx.y * 128, colBase = blockIdx.x * 128;
  gemm_tile<HID>(CTX, WOB, rowBase, colBase, As, Bs, acc);

  const int tid = threadIdx.x, lane = tid & 63, wave = tid >> 6;
  const int wm = (wave >> 1) * 64, wn = (wave & 1) * 64;
  const int l15 = lane & 15, quad = lane >> 4;
#pragma unroll
  for (int mi = 0; mi < 4; mi++)
#pragma unroll
    for (int ni = 0; ni < 4; ni++)
#pragma unroll
      for (int r = 0; r < 4; r++) {
        int row = rowBase + wm + mi * 16 + quad * 4 + r;
        int col = colBase + wn + ni * 16 + l15;
        OUT[(size_t)row * HID + col] = acc[mi][ni][r] + OB[col];
      }
}

// ---------------------------------------------------------------------------
extern "C" void kernel_launch(void* const* d_in, const int* in_sizes, int n_in,
                              void* d_out, int out_size, void* d_ws, size_t ws_size,
                              hipStream_t stream) {
  const float* x    = (const float*)d_in[0];
  const float* bw   = (const float*)d_in[1];
  const float* sw   = (const float*)d_in[2];
  const float* ss   = (const float*)d_in[3];
  const float* grid = (const float*)d_in[4];
  const float* rot  = (const float*)d_in[5];
  const float* ow   = (const float*)d_in[6];
  const float* ob   = (const float*)d_in[7];
  float* out = (float*)d_out;

  char* ws = (char*)d_ws;
  // workspace layout (bytes)
  bf16* Aact = (bf16*)(ws);                                       // 4096*9216*2 = 75,497,472
  bf16* Wp   = (bf16*)(ws + 75497472);                            // 3072*9216*2 = 56,623,104
  bf16* qr   = (bf16*)(ws + 75497472 + 56623104);                 // 8,388,608
  bf16* kr   = (bf16*)(ws + 75497472 + 56623104 + 8388608);       // 8,388,608
  bf16* vv   = (bf16*)(ws + 75497472 + 56623104 + 2 * 8388608);   // 8,388,608
  bf16* ctxb = (bf16*)(ws + 75497472 + 56623104 + 3 * 8388608);   // 8,388,608
  bf16* wob  = (bf16*)(ws + 75497472 + 56623104 + 4 * 8388608);   // 2,097,152  (total 160 MiB)

  build_a<<<NROW * HID / 256, 256, 0, stream>>>(x, grid, Aact);
  build_w<<<dim3(KA / 32, NHEAD), 256, 0, stream>>>(bw, sw, ss, rot, Wp);
  conv_wout<<<HID * HID / 1024, 256, 0, stream>>>(ow, wob);
  gemm_qkv<<<dim3(NO / 128, NROW / 128), 256, 0, stream>>>(Aact, Wp, qr, kr, vv);
  attn<<<dim3(SQ / 128, NB * NHEAD), 256, 0, stream>>>(qr, kr, vv, ctxb);
  gemm_out<<<dim3(HID / 128, NROW / 128), 256, 0, stream>>>(ctxb, wob, ob, out);
}

// Round 2
// 719.160 us; speedup vs baseline: 1.1617x; 1.1617x over previous
//
#include <hip/hip_runtime.h>
#include <cstdint>
#include <cstddef>

typedef __bf16 bf16;
typedef bf16  bf16x8 __attribute__((ext_vector_type(8)));
typedef float f32x4  __attribute__((ext_vector_type(4)));

#define GLOBAL_AS __attribute__((address_space(1)))
#define LDS_AS    __attribute__((address_space(3)))

__device__ __forceinline__ void ldg_lds16(const void* g, void* l) {
  __builtin_amdgcn_global_load_lds((const GLOBAL_AS void*)g, (LDS_AS void*)l, 16, 0, 0);
}

// problem constants
constexpr int NB    = 2;
constexpr int SQ    = 2048;
constexpr int HID   = 1024;
constexpr int NHEAD = 16;
constexpr int HD    = 64;
constexpr int NROW  = NB * SQ;        // 4096
constexpr int KA    = HID + HID * 8;  // 9216
constexpr int NO    = 3 * HID;        // 3072

// ---------------------------------------------------------------------------
// Kernel 1: A[n] = [silu(x[n,:]), b_splines(x[n,:]).flat]  (bf16)
// ---------------------------------------------------------------------------
__global__ __launch_bounds__(256) void build_a(const float* __restrict__ X,
                                               const float* __restrict__ Grid,
                                               bf16* __restrict__ A) {
  int idx = blockIdx.x * 256 + threadIdx.x;  // n*1024 + i
  int n = idx >> 10, i = idx & 1023;
  float x = X[idx];
  float s = x / (1.0f + __expf(-x));  // silu
  A[(size_t)n * KA + i] = (bf16)s;

  float kn[12];
#pragma unroll
  for (int t = 0; t < 12; t++) kn[t] = Grid[i * 12 + t];
  float bs[11];
#pragma unroll
  for (int t = 0; t < 11; t++) bs[t] = (x >= kn[t] && x < kn[t + 1]) ? 1.0f : 0.0f;
#pragma unroll
  for (int p = 1; p <= 3; p++) {
#pragma unroll
    for (int t = 0; t + p < 11; t++) {
      bs[t] = (x - kn[t]) / (kn[t + p] - kn[t]) * bs[t]
            + (kn[t + p + 1] - x) / (kn[t + p + 1] - kn[t + 1]) * bs[t + 1];
    }
  }
  union { bf16 h[8]; uint4 u; } pk;
#pragma unroll
  for (int t = 0; t < 8; t++) pk.h[t] = (bf16)bs[t];
  *(uint4*)(A + (size_t)n * KA + HID + i * 8) = pk.u;
}

// ---------------------------------------------------------------------------
// Kernel 2: pure pack (no rotation): W'[o] = [BW[o], (SW*SS)[o].flat] -> bf16
// one thread per 8 contiguous output elements.
// ---------------------------------------------------------------------------
__global__ __launch_bounds__(256) void build_w(const float* __restrict__ BW,
                                               const float* __restrict__ SW,
                                               const float* __restrict__ SS,
                                               bf16* __restrict__ Wp) {
  int idx = blockIdx.x * 256 + threadIdx.x;   // [0, 3072*1152)
  int o = idx / 1152;
  int jc = idx - o * 1152;
  float4 f0, f1;
  if (jc < 128) {
    f0 = *(const float4*)(BW + (size_t)o * HID + jc * 8);
    f1 = *(const float4*)(BW + (size_t)o * HID + jc * 8 + 4);
  } else {
    int ii = jc - 128;
    float sc = SS[(size_t)o * HID + ii];
    f0 = *(const float4*)(SW + ((size_t)o * HID + ii) * 8);
    f1 = *(const float4*)(SW + ((size_t)o * HID + ii) * 8 + 4);
    f0.x *= sc; f0.y *= sc; f0.z *= sc; f0.w *= sc;
    f1.x *= sc; f1.y *= sc; f1.z *= sc; f1.w *= sc;
  }
  union { bf16 h[8]; uint4 u; } pk;
  pk.h[0] = (bf16)f0.x; pk.h[1] = (bf16)f0.y; pk.h[2] = (bf16)f0.z; pk.h[3] = (bf16)f0.w;
  pk.h[4] = (bf16)f1.x; pk.h[5] = (bf16)f1.y; pk.h[6] = (bf16)f1.z; pk.h[7] = (bf16)f1.w;
  *(uint4*)(Wp + (size_t)o * KA + jc * 8) = pk.u;
}

// ---------------------------------------------------------------------------
// Kernel 3: out_w fp32 -> bf16
// ---------------------------------------------------------------------------
__global__ __launch_bounds__(256) void conv_wout(const float* __restrict__ OW,
                                                 bf16* __restrict__ WOB) {
  int i = (blockIdx.x * 256 + threadIdx.x) * 4;
  float4 f = *(const float4*)(OW + i);
  union { bf16 h[4]; uint2 u; } p;
  p.h[0] = (bf16)f.x; p.h[1] = (bf16)f.y; p.h[2] = (bf16)f.z; p.h[3] = (bf16)f.w;
  *(uint2*)(WOB + i) = p.u;
}

// ---------------------------------------------------------------------------
// Kernel 3b: M = 0.125 * R^T R  (64x64, symmetric, head-independent), bf16
// ---------------------------------------------------------------------------
__global__ __launch_bounds__(256) void compute_m(const float* __restrict__ R,
                                                 bf16* __restrict__ Mb) {
  __shared__ float Rl[64 * 64];
  int tid = threadIdx.x;
  for (int idx = tid; idx < 4096; idx += 256) Rl[idx] = R[idx];
  __syncthreads();
  int d = tid >> 2;
  int e0 = (tid & 3) * 16;
#pragma unroll
  for (int j = 0; j < 16; j++) {
    int e = e0 + j;
    float acc = 0.f;
#pragma unroll
    for (int m = 0; m < 64; m++) acc += Rl[m * 64 + d] * Rl[m * 64 + e];
    Mb[d * 64 + e] = (bf16)(0.125f * acc);
  }
}

// ---------------------------------------------------------------------------
// GEMM mainloop (m97 structure + XOR bank swizzle):
// C[m][n] = sum_k A[m][k] * B[n][k].  128x128 tile, BK=32, 4 waves 2x2,
// each wave 64x64 = 4x4 MFMA 16x16x32.
// LDS rows are 32 elems (64 B); chunk slot c holds global chunk c ^ ((row>>1)&3)
// so a 16-lane fragment-read group spreads over all 8 positions mod 128 B.
// ---------------------------------------------------------------------------
template <int K>
__device__ __forceinline__ void gemm_tile(const bf16* __restrict__ A,
                                          const bf16* __restrict__ Bw,
                                          int rowBase, int colBase,
                                          bf16* As, bf16* Bs, f32x4 acc[4][4]) {
  const int tid  = threadIdx.x;
  const int lane = tid & 63, wave = tid >> 6;
  const int wm = (wave >> 1) * 64, wn = (wave & 1) * 64;
  const int l15 = lane & 15, quad = lane >> 4;
  const int rA = tid >> 2;
  const int swSrc = ((tid & 3) ^ ((rA >> 1) & 3)) * 8;       // swizzled source chunk
  const int swRd  = (quad ^ ((l15 >> 1) & 3)) * 8;           // swizzled read slot
#pragma unroll
  for (int mi = 0; mi < 4; mi++)
#pragma unroll
    for (int ni = 0; ni < 4; ni++) acc[mi][ni] = (f32x4){0.f, 0.f, 0.f, 0.f};

  const bf16* Ag1 = A  + (size_t)(rowBase + rA) * K + swSrc;
  const bf16* Ag2 = A  + (size_t)(rowBase + 64 + rA) * K + swSrc;
  const bf16* Bg1 = Bw + (size_t)(colBase + rA) * K + swSrc;
  const bf16* Bg2 = Bw + (size_t)(colBase + 64 + rA) * K + swSrc;

  for (int k0 = 0; k0 < K; k0 += 32) {
    __syncthreads();
    ldg_lds16(Ag1 + k0, As + tid * 8);
    ldg_lds16(Ag2 + k0, As + 2048 + tid * 8);
    ldg_lds16(Bg1 + k0, Bs + tid * 8);
    ldg_lds16(Bg2 + k0, Bs + 2048 + tid * 8);
    __syncthreads();
    bf16x8 af[4], bfr[4];
#pragma unroll
    for (int mi = 0; mi < 4; mi++)
      af[mi] = *(const bf16x8*)(As + (wm + mi * 16 + l15) * 32 + swRd);
#pragma unroll
    for (int ni = 0; ni < 4; ni++)
      bfr[ni] = *(const bf16x8*)(Bs + (wn + ni * 16 + l15) * 32 + swRd);
#pragma unroll
    for (int mi = 0; mi < 4; mi++)
#pragma unroll
      for (int ni = 0; ni < 4; ni++)
        acc[mi][ni] = __builtin_amdgcn_mfma_f32_16x16x32_bf16(af[mi], bfr[ni], acc[mi][ni], 0, 0, 0);
  }
}

// ---------------------------------------------------------------------------
// Kernel 4: qkv = Aaug @ W'^T ; split-store q (plain), k (plain), v (plain)
// each laid out [b][h][s][d] bf16.
// ---------------------------------------------------------------------------
__global__ __launch_bounds__(256) void gemm_qkv(const bf16* __restrict__ A,
                                                const bf16* __restrict__ W,
                                                bf16* __restrict__ QQ,
                                                bf16* __restrict__ KK,
                                                bf16* __restrict__ VV) {
  __shared__ __align__(16) bf16 As[128 * 32];
  __shared__ __align__(16) bf16 Bs[128 * 32];
  f32x4 acc[4][4];
  const int rowBase = blockIdx.y * 128, colBase = blockIdx.x * 128;
  gemm_tile<KA>(A, W, rowBase, colBase, As, Bs, acc);

  const int tid = threadIdx.x, lane = tid & 63, wave = tid >> 6;
  const int wm = (wave >> 1) * 64, wn = (wave & 1) * 64;
  const int l15 = lane & 15, quad = lane >> 4;
#pragma unroll
  for (int mi = 0; mi < 4; mi++)
#pragma unroll
    for (int ni = 0; ni < 4; ni++)
#pragma unroll
      for (int r = 0; r < 4; r++) {
        int row = rowBase + wm + mi * 16 + quad * 4 + r;  // n = b*2048+s
        int col = colBase + wn + ni * 16 + l15;           // o = h*192+c
        int b = row >> 11, s = row & 2047;
        int hh = col / 192, c = col - hh * 192;
        size_t base = ((size_t)(b * NHEAD + hh) * SQ + s) * HD;
        float v = acc[mi][ni][r];
        if (c < 64)        QQ[base + c] = (bf16)v;
        else if (c < 128)  KK[base + c - 64] = (bf16)v;
        else               VV[base + c - 128] = (bf16)v;
      }
}

// ---------------------------------------------------------------------------
// Kernel 4b: kr = kk @ M  (M symmetric 64x64, 0.125 folded in). 128-row tiles.
// ---------------------------------------------------------------------------
__global__ __launch_bounds__(256) void rot_k(const bf16* __restrict__ KK,
                                             const bf16* __restrict__ Mb,
                                             bf16* __restrict__ KR) {
  __shared__ __align__(16) bf16 Ks[128 * 64];
  __shared__ __align__(16) bf16 Ms[64 * 64];
  const int rowBase = blockIdx.x * 128;  // over 65536 rows
  const int tid = threadIdx.x, lane = tid & 63, wave = tid >> 6;
  const int l15 = lane & 15, quad = lane >> 4;
  const int sw8 = l15 & 7;

#pragma unroll
  for (int i = 0; i < 4; i++) {
    int c = i * 256 + tid, row = c >> 3, seg = c & 7;
    ldg_lds16(KK + (size_t)(rowBase + row) * HD + ((seg ^ (row & 7)) * 8), Ks + c * 8);
  }
#pragma unroll
  for (int i = 0; i < 2; i++) {
    int c = i * 256 + tid, row = c >> 3, seg = c & 7;
    ldg_lds16(Mb + row * 64 + ((seg ^ (row & 7)) * 8), Ms + c * 8);
  }
  __syncthreads();

  f32x4 acc[2][4];
#pragma unroll
  for (int mi = 0; mi < 2; mi++)
#pragma unroll
    for (int nj = 0; nj < 4; nj++) acc[mi][nj] = (f32x4){0.f, 0.f, 0.f, 0.f};
#pragma unroll
  for (int kc = 0; kc < 2; kc++) {
    bf16x8 af[2], bfr[4];
#pragma unroll
    for (int mi = 0; mi < 2; mi++)
      af[mi] = *(const bf16x8*)(Ks + (wave * 32 + mi * 16 + l15) * 64 + (((kc * 4 + quad) ^ sw8) * 8));
#pragma unroll
    for (int nj = 0; nj < 4; nj++)
      bfr[nj] = *(const bf16x8*)(Ms + (nj * 16 + l15) * 64 + (((kc * 4 + quad) ^ sw8) * 8));
#pragma unroll
    for (int mi = 0; mi < 2; mi++)
#pragma unroll
      for (int nj = 0; nj < 4; nj++)
        acc[mi][nj] = __builtin_amdgcn_mfma_f32_16x16x32_bf16(af[mi], bfr[nj], acc[mi][nj], 0, 0, 0);
  }
#pragma unroll
  for (int mi = 0; mi < 2; mi++)
#pragma unroll
    for (int nj = 0; nj < 4; nj++)
#pragma unroll
      for (int r = 0; r < 4; r++) {
        int row = rowBase + wave * 32 + mi * 16 + quad * 4 + r;
        KR[(size_t)row * HD + nj * 16 + l15] = (bf16)acc[mi][nj][r];
      }
}

// ---------------------------------------------------------------------------
// Kernel 4c: VT[bh][d][s] = VV[bh][s][d]  (64x64 LDS tile transpose)
// ---------------------------------------------------------------------------
__global__ __launch_bounds__(256) void transpose_v(const bf16* __restrict__ VV,
                                                   bf16* __restrict__ VT) {
  __shared__ __align__(16) bf16 Ts[64 * 72];
  const int st = blockIdx.x, bh = blockIdx.y, tid = threadIdx.x;
  const bf16* src = VV + ((size_t)bh * SQ + st * 64) * HD;
#pragma unroll
  for (int i = 0; i < 2; i++) {
    int c = i * 256 + tid, row = c >> 3, seg = c & 7;
    bf16x8 v8 = *(const bf16x8*)(src + row * HD + seg * 8);
    *(bf16x8*)(&Ts[row * 72 + seg * 8]) = v8;
  }
  __syncthreads();
#pragma unroll
  for (int i = 0; i < 2; i++) {
    int c = i * 256 + tid, drow = c >> 3, seg = c & 7;
    bf16x8 o8;
#pragma unroll
    for (int j = 0; j < 8; j++) o8[j] = Ts[(seg * 8 + j) * 72 + drow];
    *(bf16x8*)(VT + ((size_t)bh * HD + drow) * SQ + st * 64 + seg * 8) = o8;
  }
}

// ---------------------------------------------------------------------------
// Kernel 5: flash attention, all LDS tiles XOR-swizzled (64-elem rows:
// slot = chunk ^ (row&7) spreads 16-lane groups over all 8 positions/128B).
// Q plain, K pre-rotated (scale inside M), V pre-transposed [d][s].
// ---------------------------------------------------------------------------
__global__ __launch_bounds__(256) void attn(const bf16* __restrict__ QQ,
                                            const bf16* __restrict__ KR,
                                            const bf16* __restrict__ VT,
                                            bf16* __restrict__ CTXB) {
  __shared__ __align__(16) bf16 Qs[128 * 64];
  __shared__ __align__(16) bf16 Ks[64 * 64];
  __shared__ __align__(16) bf16 Vt[64 * 64];   // [d][key]
  __shared__ __align__(16) bf16 Ps[128 * 64];
  const int bh = blockIdx.y;
  const int b = bh >> 4, h = bh & 15;
  const int qbase = blockIdx.x * 128;
  const bf16* Q  = QQ + (size_t)bh * SQ * HD;
  const bf16* Kp = KR + (size_t)bh * SQ * HD;
  const bf16* Vp = VT + (size_t)bh * HD * SQ;
  const int tid = threadIdx.x, lane = tid & 63, wave = tid >> 6;
  const int l15 = lane & 15, quad = lane >> 4;
  const int sw8 = l15 & 7;

  // stage Q tile (128 x 64), swizzled
#pragma unroll
  for (int i = 0; i < 4; i++) {
    int c = i * 256 + tid, row = c >> 3, seg = c & 7;
    ldg_lds16(Q + (size_t)(qbase + row) * HD + ((seg ^ (row & 7)) * 8), Qs + c * 8);
  }

  float mstate[2][4], lstate[2][4];
  f32x4 ctxacc[2][4];
#pragma unroll
  for (int mi = 0; mi < 2; mi++)
#pragma unroll
    for (int r = 0; r < 4; r++) { mstate[mi][r] = -1e30f; lstate[mi][r] = 0.f; }
#pragma unroll
  for (int mi = 0; mi < 2; mi++)
#pragma unroll
    for (int nd = 0; nd < 4; nd++) ctxacc[mi][nd] = (f32x4){0.f, 0.f, 0.f, 0.f};

  for (int kt = 0; kt < SQ / 64; kt++) {
    const int kbase = kt * 64;
    if (kt) __syncthreads();
#pragma unroll
    for (int i = 0; i < 2; i++) {
      int c = i * 256 + tid, row = c >> 3, seg = c & 7;
      ldg_lds16(Kp + (size_t)(kbase + row) * HD + ((seg ^ (row & 7)) * 8), Ks + c * 8);
    }
#pragma unroll
    for (int i = 0; i < 2; i++) {
      int c = i * 256 + tid, row = c >> 3, seg = c & 7;  // row = d
      ldg_lds16(Vp + (size_t)row * SQ + kbase + ((seg ^ (row & 7)) * 8), Vt + c * 8);
    }
    __syncthreads();

    // S = Q K^T
    f32x4 sacc[2][4];
#pragma unroll
    for (int mi = 0; mi < 2; mi++)
#pragma unroll
      for (int nj = 0; nj < 4; nj++) sacc[mi][nj] = (f32x4){0.f, 0.f, 0.f, 0.f};
#pragma unroll
    for (int kc = 0; kc < 2; kc++) {
      const int slot = ((kc * 4 + quad) ^ sw8) * 8;
      bf16x8 af[2], bfr[4];
#pragma unroll
      for (int mi = 0; mi < 2; mi++)
        af[mi] = *(const bf16x8*)(Qs + (wave * 32 + mi * 16 + l15) * 64 + slot);
#pragma unroll
      for (int nj = 0; nj < 4; nj++)
        bfr[nj] = *(const bf16x8*)(Ks + (nj * 16 + l15) * 64 + slot);
#pragma unroll
      for (int mi = 0; mi < 2; mi++)
#pragma unroll
        for (int nj = 0; nj < 4; nj++)
          sacc[mi][nj] = __builtin_amdgcn_mfma_f32_16x16x32_bf16(af[mi], bfr[nj], sacc[mi][nj], 0, 0, 0);
    }

    // online softmax per owned row
#pragma unroll
    for (int mi = 0; mi < 2; mi++) {
#pragma unroll
      for (int r = 0; r < 4; r++) {
        float tm = -1e30f;
#pragma unroll
        for (int nj = 0; nj < 4; nj++) tm = fmaxf(tm, sacc[mi][nj][r]);
#pragma unroll
        for (int off = 1; off < 16; off <<= 1) tm = fmaxf(tm, __shfl_xor(tm, off));
        float mold = mstate[mi][r];
        float mnew = fmaxf(mold, tm);
        float alpha = __expf(mold - mnew);
        float rs = 0.f;
#pragma unroll
        for (int nj = 0; nj < 4; nj++) {
          float p = __expf(sacc[mi][nj][r] - mnew);
          sacc[mi][nj][r] = p;
          rs += p;
        }
#pragma unroll
        for (int off = 1; off < 16; off <<= 1) rs += __shfl_xor(rs, off);
        lstate[mi][r] = lstate[mi][r] * alpha + rs;
        mstate[mi][r] = mnew;
#pragma unroll
        for (int nd = 0; nd < 4; nd++) ctxacc[mi][nd][r] *= alpha;
      }
      // write P (C/D layout) -> LDS, swizzled
#pragma unroll
      for (int nj = 0; nj < 4; nj++)
#pragma unroll
        for (int r = 0; r < 4; r++) {
          int prow = wave * 32 + mi * 16 + quad * 4 + r;
          int slot = ((nj * 2 + (l15 >> 3)) ^ (prow & 7)) * 8 + (l15 & 7);
          Ps[prow * 64 + slot] = (bf16)sacc[mi][nj][r];
        }
    }
    __syncthreads();

    // ctx += P V
#pragma unroll
    for (int kc = 0; kc < 2; kc++) {
      const int slot = ((kc * 4 + quad) ^ sw8) * 8;
      bf16x8 af[2], bfr[4];
#pragma unroll
      for (int mi = 0; mi < 2; mi++)
        af[mi] = *(const bf16x8*)(Ps + (wave * 32 + mi * 16 + l15) * 64 + slot);
#pragma unroll
      for (int nd = 0; nd < 4; nd++)
        bfr[nd] = *(const bf16x8*)(Vt + (nd * 16 + l15) * 64 + slot);
#pragma unroll
      for (int mi = 0; mi < 2; mi++)
#pragma unroll
        for (int nd = 0; nd < 4; nd++)
          ctxacc[mi][nd] = __builtin_amdgcn_mfma_f32_16x16x32_bf16(af[mi], bfr[nd], ctxacc[mi][nd], 0, 0, 0);
    }
  }

  // epilogue
#pragma unroll
  for (int mi = 0; mi < 2; mi++)
#pragma unroll
    for (int nd = 0; nd < 4; nd++)
#pragma unroll
      for (int r = 0; r < 4; r++) {
        int srow = qbase + wave * 32 + mi * 16 + quad * 4 + r;
        float val = ctxacc[mi][nd][r] / lstate[mi][r];
        CTXB[(size_t)(b * SQ + srow) * HID + h * HD + nd * 16 + l15] = (bf16)val;
      }
}

// ---------------------------------------------------------------------------
// Kernel 6: out = ctx @ out_w^T + out_b
// ---------------------------------------------------------------------------
__global__ __launch_bounds__(256) void gemm_out(const bf16* __restrict__ CTX,
                                                const bf16* __restrict__ WOB,
                                                const float* __restrict__ OB,
                                                float* __restrict__ OUT) {
  __shared__ __align__(16) bf16 As[128 * 32];
  __shared__ __align__(16) bf16 Bs[128 * 32];
  f32x4 acc[4][4];
  const int rowBase = blockIdx.y * 128, colBase = blockIdx.x * 128;
  gemm_tile<HID>(CTX, WOB, rowBase, colBase, As, Bs, acc);

  const int tid = threadIdx.x, lane = tid & 63, wave = tid >> 6;
  const int wm = (wave >> 1) * 64, wn = (wave & 1) * 64;
  const int l15 = lane & 15, quad = lane >> 4;
#pragma unroll
  for (int mi = 0; mi < 4; mi++)
#pragma unroll
    for (int ni = 0; ni < 4; ni++)
#pragma unroll
      for (int r = 0; r < 4; r++) {
        int row = rowBase + wm + mi * 16 + quad * 4 + r;
        int col = colBase + wn + ni * 16 + l15;
        OUT[(size_t)row * HID + col] = acc[mi][ni][r] + OB[col];
      }
}

// ---------------------------------------------------------------------------
extern "C" void kernel_launch(void* const* d_in, const int* in_sizes, int n_in,
                              void* d_out, int out_size, void* d_ws, size_t ws_size,
                              hipStream_t stream) {
  const float* x    = (const float*)d_in[0];
  const float* bw   = (const float*)d_in[1];
  const float* sw   = (const float*)d_in[2];
  const float* ss   = (const float*)d_in[3];
  const float* grid = (const float*)d_in[4];
  const float* rot  = (const float*)d_in[5];
  const float* ow   = (const float*)d_in[6];
  const float* ob   = (const float*)d_in[7];
  float* out = (float*)d_out;

  char* ws = (char*)d_ws;
  // workspace layout (total 160 MiB, same as round 1):
  bf16* Aact = (bf16*)(ws);                          // 75,497,472 B (dead after gemm_qkv)
  bf16* kr   = (bf16*)(ws);                          // reuse: 8,388,608
  bf16* vt   = (bf16*)(ws + 8388608);                // reuse: 8,388,608
  bf16* Mb   = (bf16*)(ws + 16777216);               // reuse: 8,192
  bf16* Wp   = (bf16*)(ws + 75497472);               // 56,623,104
  bf16* qq   = (bf16*)(ws + 132120576);              // 8,388,608
  bf16* kk   = (bf16*)(ws + 140509184);              // 8,388,608
  bf16* vv   = (bf16*)(ws + 148897792);              // 8,388,608
  bf16* ctxb = (bf16*)(ws + 157286400);              // 8,388,608
  bf16* wob  = (bf16*)(ws + 165675008);              // 2,097,152 -> end 167,772,160

  build_a<<<NROW * HID / 256, 256, 0, stream>>>(x, grid, Aact);
  build_w<<<NO * (KA / 8) / 256, 256, 0, stream>>>(bw, sw, ss, Wp);
  conv_wout<<<HID * HID / 1024, 256, 0, stream>>>(ow, wob);
  gemm_qkv<<<dim3(NO / 128, NROW / 128), 256, 0, stream>>>(Aact, Wp, qq, kk, vv);
  compute_m<<<1, 256, 0, stream>>>(rot, Mb);          // after gemm_qkv: Aact region now dead
  rot_k<<<NB * NHEAD * SQ / 128, 256, 0, stream>>>(kk, Mb, kr);
  transpose_v<<<dim3(SQ / 64, NB * NHEAD), 256, 0, stream>>>(vv, vt);
  attn<<<dim3(SQ / 128, NB * NHEAD), 256, 0, stream>>>(qq, kr, vt, ctxb);
  gemm_out<<<dim3(HID / 128, NROW / 128), 256, 0, stream>>>(ctxb, wob, ob, out);
}